// Round 9
// baseline (124.537 us; speedup 1.0000x reference)
//
#include <hip/hip_runtime.h>
#include <hip/hip_fp16.h>

#define B_ 16
#define D_ 128
#define T_ 4096
#define C_ 1024
#define N_ (B_*T_)
#define MARGIN 1.5e-3f
#define RB 8

typedef __attribute__((ext_vector_type(8))) __fp16 fp16x8;
typedef __attribute__((ext_vector_type(4))) float f32x4;
typedef unsigned int u32;
typedef unsigned short u16;

static __device__ __forceinline__ fp16x8 as_fp16x8(int4 v) {
    union { int4 i; fp16x8 h; } u; u.i = v; return u.h;
}
static __device__ __forceinline__ u32 pack_h2(float a, float b) {
    return (u32)__half_as_ushort(__float2half(a)) |
           ((u32)__half_as_ushort(__float2half(b)) << 16);
}

// ---------------- init ----------------
__global__ __launch_bounds__(256) void vq_init_kernel(float* used, float* accum, int* nflag) {
    int tid = blockIdx.x * 256 + threadIdx.x;
    if (tid < C_) used[tid] = 0.0f;
    if (tid == 0) { accum[0] = 0.0f; nflag[0] = 0; }
}

// ---------------- e2[c] = ||embed_c||^2, numpy pairwise-8 replica ----------------
__global__ __launch_bounds__(256) void vq_e2_kernel(const float* __restrict__ embed,
                                                    float* __restrict__ e2) {
#pragma clang fp contract(off)
    int c = blockIdx.x * 256 + threadIdx.x;
    const float* row = embed + (size_t)c * D_;
    float r[8];
#pragma unroll
    for (int j = 0; j < 8; ++j) { float v = row[j]; r[j] = v * v; }
    for (int i = 8; i < D_; i += 8) {
#pragma unroll
        for (int j = 0; j < 8; ++j) { float v = row[i + j]; r[j] = r[j] + v * v; }
    }
    e2[c] = ((r[0] + r[1]) + (r[2] + r[3])) + ((r[4] + r[5]) + (r[6] + r[7]));
}

// ---------------- prep: split embed into fp16 hi/lo (wave-tile-major) + fp32 transpose eT ----------------
// epk layout (u32 units): chunk(rnd,w,t)=rnd*16+w*4+t ; index = chunk*256 + l*4 + j2
// content of (c, d2): c = rnd*64+w*16+(l&15) ; d2 = 16t+4*(l>>4)+j2   (d2 = dim-pair index)
__global__ __launch_bounds__(256) void vq_eprep_kernel(const float* __restrict__ embed,
                                                       u32* __restrict__ epk_hi,
                                                       u32* __restrict__ epk_lo,
                                                       float* __restrict__ eT) {
    int i = blockIdx.x * 256 + threadIdx.x;    // pair index, C_*D_/2 = 65536 total
    int c = i >> 6, d2 = i & 63;
    float2 v = reinterpret_cast<const float2*>(embed)[i];
    __half h0 = __float2half(v.x), h1 = __float2half(v.y);
    float l0 = v.x - __half2float(h0), l1 = v.y - __half2float(h1);
    u32 hp = (u32)__half_as_ushort(h0) | ((u32)__half_as_ushort(h1) << 16);
    u32 lp = (u32)__half_as_ushort(__float2half(l0)) |
             ((u32)__half_as_ushort(__float2half(l1)) << 16);
    int chunk = (c >> 6) * 16 + ((c >> 4) & 3) * 4 + (d2 >> 4);
    int oi = chunk * 256 + (((d2 >> 2) & 3) * 16 + (c & 15)) * 4 + (d2 & 3);
    epk_hi[oi] = hp;
    epk_lo[oi] = lp;
    int d0 = d2 * 2;
    eT[(size_t)d0 * C_ + c]       = v.x;
    eT[(size_t)(d0 + 1) * C_ + c] = v.y;
}

// ---------------- MFMA prefilter argmin (fp16 2-term, x-frags in VGPRs, no in-loop LDS) ----------------
// 1024 blocks x 4 waves. Block = 64 points; wave w covers codes {rnd*64 + w*16 .. +15}, rnd=0..15.
__global__ __launch_bounds__(256, 4) void vq_mfma_kernel(
    const float* __restrict__ x, const u32* __restrict__ epk_hi, const u32* __restrict__ epk_lo,
    const float* __restrict__ e2, float* __restrict__ idx_f, int* __restrict__ idx_i,
    int* __restrict__ flagged, int* __restrict__ nflag)
{
    __shared__ float mv1[4][64];
    __shared__ int   mi1[4][64];
    __shared__ float mv2[4][64];

    const int g  = blockIdx.x;
    const int b  = g >> 6;
    const int t0 = (g & 63) << 6;
    const int tid = threadIdx.x;
    const int w  = tid >> 6;      // wave 0..3
    const int l  = tid & 63;
    const int r  = l & 15;        // point col / code row within 16x16 tile
    const int q  = l >> 4;        // k-group

    // ---- one-time: gather x fragments (fp16 RNE hi) into 64 VGPRs ----
    // strip s: point t0+16s+r ; kstep t: dims 32t + 8q + j
    fp16x8 xh[4][4];
    {
        const float* xp = x + (size_t)b * ((size_t)D_ * T_) + t0 + r;
#pragma unroll
        for (int s = 0; s < 4; ++s) {
#pragma unroll
            for (int t = 0; t < 4; ++t) {
                float f[8];
#pragma unroll
                for (int j = 0; j < 8; ++j)
                    f[j] = xp[16 * s + (size_t)(32 * t + 8 * q + j) * T_];
                int4 pk;
                pk.x = (int)pack_h2(f[0], f[1]);
                pk.y = (int)pack_h2(f[2], f[3]);
                pk.z = (int)pack_h2(f[4], f[5]);
                pk.w = (int)pack_h2(f[6], f[7]);
                xh[s][t] = as_fp16x8(pk);
            }
        }
    }

    float rv1[4], rv2[4];
    int   ri1[4];
#pragma unroll
    for (int s = 0; s < 4; ++s) { rv1[s] = 3.4e38f; rv2[s] = 3.4e38f; ri1[s] = 0; }

    // per-lane e base (u32): wave w chunk base = w*4*256, + l*4 within chunk
    const u32* ephi = epk_hi + w * 1024 + l * 4;
    const u32* eplo = epk_lo + w * 1024 + l * 4;
    const int cbaseq = w * 16 + 4 * q;

    for (int rnd = 0; rnd < 16; ++rnd) {
        f32x4 eev = *reinterpret_cast<const f32x4*>(e2 + rnd * 64 + cbaseq);
        f32x4 acc[4];
#pragma unroll
        for (int s = 0; s < 4; ++s) acc[s] = f32x4{0.f, 0.f, 0.f, 0.f};

        __builtin_amdgcn_s_setprio(1);
#pragma unroll
        for (int t = 0; t < 4; ++t) {
            int4 eh = *reinterpret_cast<const int4*>(ephi + t * 256);
            int4 el = *reinterpret_cast<const int4*>(eplo + t * 256);
#pragma unroll
            for (int s = 0; s < 4; ++s) {
                acc[s] = __builtin_amdgcn_mfma_f32_16x16x32_f16(as_fp16x8(eh), xh[s][t], acc[s], 0, 0, 0);
                acc[s] = __builtin_amdgcn_mfma_f32_16x16x32_f16(as_fp16x8(el), xh[s][t], acc[s], 0, 0, 0);
            }
        }
        __builtin_amdgcn_s_setprio(0);
        ephi += 4096; eplo += 4096;

        // D: col = l&15 -> point 16s+r ; row = 4q+reg -> code rnd*64 + w*16 + 4q + reg
#pragma unroll
        for (int s = 0; s < 4; ++s) {
#pragma unroll
            for (int reg = 0; reg < 4; ++reg) {
                float sc = fmaf(-2.0f, acc[s][reg], eev[reg]);
                int c = rnd * 64 + cbaseq + reg;
                if (sc < rv1[s]) { rv2[s] = rv1[s]; rv1[s] = sc; ri1[s] = c; }
                else rv2[s] = fminf(rv2[s], sc);
            }
        }
    }

    // ---- merge across the 4 q-lane-groups per strip (within wave) ----
#pragma unroll
    for (int s = 0; s < 4; ++s) {
        float v1 = rv1[s], v2 = rv2[s];
        int   i1 = ri1[s];
#pragma unroll
        for (int mo = 0; mo < 2; ++mo) {
            int m = 16 << mo;
            float ov1 = __shfl_xor(v1, m, 64);
            int   oi1 = __shfl_xor(i1, m, 64);
            float ov2 = __shfl_xor(v2, m, 64);
            float nv2 = fminf(fmaxf(v1, ov1), fminf(v2, ov2));
            if (ov1 < v1 || (ov1 == v1 && oi1 < i1)) { v1 = ov1; i1 = oi1; }
            v2 = nv2;
        }
        if (q == 0) { mv1[w][16 * s + r] = v1; mi1[w][16 * s + r] = i1; mv2[w][16 * s + r] = v2; }
    }
    __syncthreads();

    // ---- merge across waves; write provisional idx; flag near-ties ----
    if (tid < 64) {
        float V1 = 3.4e38f, V2 = 3.4e38f;
        int   I1 = 0;
#pragma unroll
        for (int w2 = 0; w2 < 4; ++w2) {
            float a1 = mv1[w2][tid]; int ai = mi1[w2][tid]; float a2 = mv2[w2][tid];
            if (a1 < V1 || (a1 == V1 && ai < I1)) { V2 = fminf(V2, V1); V1 = a1; I1 = ai; }
            else V2 = fminf(V2, a1);
            V2 = fminf(V2, a2);
        }
        int n = g * 64 + tid;
        idx_i[n] = I1;
        idx_f[n] = (float)I1;
        if (V2 - V1 < MARGIN) { int pos = atomicAdd(nflag, 1); flagged[pos] = n; }
    }
}

// ---------------- exact numpy-replica rescore of flagged points (batched x8) ----------------
// Block-iteration = 8 points; each eT row load is FMA'd into 8 point-accumulators.
__global__ __launch_bounds__(256) void vq_refine_kernel(
    const float* __restrict__ x, const float* __restrict__ eT,
    const float* __restrict__ e2,
    const int* __restrict__ flagged, const int* __restrict__ nflag,
    float* __restrict__ idx_f, int* __restrict__ idx_i)
{
    __shared__ float xs[RB][D_];
    __shared__ float r8s[RB][8];
    __shared__ float xxs[RB];
    __shared__ float wvv[RB][4];
    __shared__ int   wvi[RB][4];

    const int tid = threadIdx.x;
    const int wv_ = tid >> 6;
    const int l   = tid & 63;
    const int total = *nflag;

    for (int base = blockIdx.x * RB; base < total; base += gridDim.x * RB) {
        __syncthreads();                       // guard LDS reuse across iterations
        // stage 8 x-vectors (zeros for out-of-range slots)
#pragma unroll
        for (int e = 0; e < RB * D_ / 256; ++e) {
            int idx = tid + e * 256;
            int k = idx >> 7, d = idx & 127;
            float v = 0.f;
            int fi = base + k;
            if (fi < total) {
                int n = flagged[fi];
                int bb = n >> 12, t = n & (T_ - 1);
                v = x[(size_t)bb * ((size_t)D_ * T_) + (size_t)d * T_ + t];
            }
            xs[k][d] = v;
        }
        __syncthreads();

        // xx = np.sum(x*x) pairwise-8 replica, 8 chains per point in parallel
        if (tid < RB * 8) {
#pragma clang fp contract(off)
            int k = tid >> 3, j = tid & 7;
            float v0 = xs[k][j];
            float rj = v0 * v0;
            for (int i = 8; i < D_; i += 8) { float v = xs[k][i + j]; rj = rj + v * v; }
            r8s[k][j] = rj;
        }
        __syncthreads();
        if (tid < RB) {
#pragma clang fp contract(off)
            xxs[tid] = ((r8s[tid][0] + r8s[tid][1]) + (r8s[tid][2] + r8s[tid][3]))
                     + ((r8s[tid][4] + r8s[tid][5]) + (r8s[tid][6] + r8s[tid][7]));
        }
        __syncthreads();

        // lane handles codes c = wv_*256 + 64*k2 + l (k2=0..3) x 8 points
        float acc[4][RB];
#pragma unroll
        for (int k2 = 0; k2 < 4; ++k2)
#pragma unroll
            for (int k = 0; k < RB; ++k) acc[k2][k] = 0.f;

        const float* ep = eT + wv_ * 256 + l;
        for (int d = 0; d < D_; ++d) {
            const float* rowp = ep + (size_t)d * C_;
            float ev0 = rowp[0], ev1 = rowp[64], ev2 = rowp[128], ev3 = rowp[192];
#pragma unroll
            for (int k = 0; k < RB; ++k) {
                float xv = xs[k][d];
                acc[0][k] = fmaf(xv, ev0, acc[0][k]);
                acc[1][k] = fmaf(xv, ev1, acc[1][k]);
                acc[2][k] = fmaf(xv, ev2, acc[2][k]);
                acc[3][k] = fmaf(xv, ev3, acc[3][k]);
            }
        }

        float e2v[4];
#pragma unroll
        for (int k2 = 0; k2 < 4; ++k2) e2v[k2] = e2[wv_ * 256 + 64 * k2 + l];

#pragma unroll
        for (int k = 0; k < RB; ++k) {
            float xx = xxs[k];
            float best = 3.4e38f;
            int   bi = 0;
#pragma unroll
            for (int k2 = 0; k2 < 4; ++k2) {
                int c = wv_ * 256 + 64 * k2 + l;
                float s;
                {
#pragma clang fp contract(off)
                    s = (xx - 2.0f * acc[k2][k]) + e2v[k2];
                }
                if (s < best) { best = s; bi = c; }   // ascending c within lane
            }
#pragma unroll
            for (int m = 1; m <= 32; m <<= 1) {
                float ov = __shfl_xor(best, m, 64);
                int   oc = __shfl_xor(bi, m, 64);
                if (ov < best || (ov == best && oc < bi)) { best = ov; bi = oc; }
            }
            if (l == 0) { wvv[k][wv_] = best; wvi[k][wv_] = bi; }
        }
        __syncthreads();
        if (tid < RB) {
            int k = tid;
            if (base + k < total) {
                float V = wvv[k][0]; int I = wvi[k][0];
#pragma unroll
                for (int w2 = 1; w2 < 4; ++w2)
                    if (wvv[k][w2] < V || (wvv[k][w2] == V && wvi[k][w2] < I)) { V = wvv[k][w2]; I = wvi[k][w2]; }
                int n = flagged[base + k];
                idx_i[n] = I;
                idx_f[n] = (float)I;
            }
        }
    }
}

// ---------------- gather + loss partials + used-flags ----------------
__global__ __launch_bounds__(256) void vq_gather_kernel(
    const float* __restrict__ x, const float* __restrict__ embed,
    const int* __restrict__ idx_i, float* __restrict__ out_q,
    float* __restrict__ accum, float* __restrict__ used)
{
    __shared__ int sidx[64];
    __shared__ float red[256];

    const int g  = blockIdx.x;
    const int b  = g >> 6;
    const int t0 = (g & 63) << 6;
    const int tid = threadIdx.x;

    if (tid < 64) {
        int ci = idx_i[g * 64 + tid];
        sidx[tid] = ci;
        used[ci] = 1.0f;
    }
    __syncthreads();

    const float* xb = x     + (size_t)b * ((size_t)D_ * T_) + t0;
    float*       ob = out_q + (size_t)b * ((size_t)D_ * T_) + t0;

    float local = 0.f;
#pragma unroll
    for (int k = 0; k < 32; ++k) {
        int e = tid + 256 * k;
        int d = e >> 6, tt = e & 63;
        float qv = embed[(size_t)sidx[tt] * D_ + d];
        float xv = xb[(size_t)d * T_ + tt];
        ob[(size_t)d * T_ + tt] = qv;
        float df = xv - qv;
        local += df * df;
    }

    red[tid] = local;
    __syncthreads();
    for (int st = 128; st > 0; st >>= 1) {
        if (tid < st) red[tid] += red[tid + st];
        __syncthreads();
    }
    if (tid == 0) atomicAdd(accum, red[0]);
}

// ---------------- finalize ----------------
__global__ __launch_bounds__(256) void vq_final_kernel(
    const float* __restrict__ used, const float* __restrict__ accum,
    float* __restrict__ out_loss, float* __restrict__ out_util)
{
    __shared__ float red[256];
    int tid = threadIdx.x;
    float s = 0.f;
    for (int k = tid; k < C_; k += 256) s += used[k];
    red[tid] = s;
    __syncthreads();
    for (int st = 128; st > 0; st >>= 1) {
        if (tid < st) red[tid] += red[tid + st];
        __syncthreads();
    }
    if (tid == 0) {
        out_loss[0] = 2.0f * accum[0] / (float)((size_t)N_ * D_);
        out_util[0] = red[0] / (float)C_;
    }
}

extern "C" void kernel_launch(void* const* d_in, const int* in_sizes, int n_in,
                              void* d_out, int out_size, void* d_ws, size_t ws_size,
                              hipStream_t stream) {
    const float* x     = (const float*)d_in[0];
    const float* embed = (const float*)d_in[1];

    float* out      = (float*)d_out;
    float* out_q    = out;                              // 8388608
    float* idx_f    = out + (size_t)B_ * D_ * T_;       // 65536
    float* out_loss = idx_f + N_;                       // 1
    float* out_util = out_loss + 1;                     // 1

    float* ws      = (float*)d_ws;
    float* e2      = ws;                                 // [0 .. 1024)
    float* used    = ws + 1024;                          // [1024 .. 2048)
    int*   idx_i   = (int*)(ws + 2048);                  // [2048 .. 67584)
    float* accum   = ws + 67584;                         // [67584]
    int*   nflag   = (int*)(ws + 67585);                 // [67585]
    int*   flagged = (int*)(ws + 67588);                 // [67588 .. 133124)
    u32*   epk_hi  = (u32*)(ws + 133124);                // 65536 u32, 16B-aligned
    u32*   epk_lo  = (u32*)(ws + 198660);                // 65536 u32, 16B-aligned
    float* eT      = ws + 264196;                        // 131072 f32, 16B-aligned

    vq_init_kernel  <<<4, 256, 0, stream>>>(used, accum, nflag);
    vq_e2_kernel    <<<C_ / 256, 256, 0, stream>>>(embed, e2);
    vq_eprep_kernel <<<C_ * D_ / 2 / 256, 256, 0, stream>>>(embed, epk_hi, epk_lo, eT);
    vq_mfma_kernel  <<<N_ / 64, 256, 0, stream>>>(x, epk_hi, epk_lo, e2, idx_f, idx_i, flagged, nflag);
    vq_refine_kernel<<<256, 256, 0, stream>>>(x, eT, e2, flagged, nflag, idx_f, idx_i);
    vq_gather_kernel<<<N_ / 64, 256, 0, stream>>>(x, embed, idx_i, out_q, accum, used);
    vq_final_kernel <<<1, 256, 0, stream>>>(used, accum, out_loss, out_util);
}

// Round 10
// 102.906 us; speedup vs baseline: 1.2102x; 1.2102x over previous
//
#include <hip/hip_runtime.h>
#include <hip/hip_fp16.h>

#define B_ 16
#define D_ 128
#define T_ 4096
#define C_ 1024
#define N_ (B_*T_)
#define MARGIN 1.5e-3f
#define RB 8

typedef __attribute__((ext_vector_type(8))) __fp16 fp16x8;
typedef __attribute__((ext_vector_type(4))) float f32x4;
typedef __attribute__((ext_vector_type(4))) int i32x4;
typedef unsigned int u32;

static __device__ __forceinline__ fp16x8 as_fp16x8(i32x4 v) {
    union { i32x4 i; fp16x8 h; } u; u.i = v; return u.h;
}
static __device__ __forceinline__ u32 pack_h2(float a, float b) {
    return (u32)__half_as_ushort(__float2half(a)) |
           ((u32)__half_as_ushort(__float2half(b)) << 16);
}

// ---------------- fused prep: init + e2 (np pairwise-8 replica) + fp16 split + eT transpose ----------------
// 256 blocks x 256 thr; gid = pair index over C*D/2 = 65536.
__global__ __launch_bounds__(256) void vq_prep_kernel(
    const float* __restrict__ embed, float* __restrict__ e2,
    u32* __restrict__ epk_hi, u32* __restrict__ epk_lo, float* __restrict__ eT,
    float* __restrict__ used, float* __restrict__ accum, int* __restrict__ nflag)
{
    int gid = blockIdx.x * 256 + threadIdx.x;
    int c = gid >> 6, d2 = gid & 63;

    // fp16 hi/lo split, wave-tile-major layout (same as rounds 8/9, verified)
    float2 v = reinterpret_cast<const float2*>(embed)[gid];
    __half h0 = __float2half(v.x), h1 = __float2half(v.y);
    float l0 = v.x - __half2float(h0), l1 = v.y - __half2float(h1);
    u32 hp = (u32)__half_as_ushort(h0) | ((u32)__half_as_ushort(h1) << 16);
    u32 lp = (u32)__half_as_ushort(__float2half(l0)) |
             ((u32)__half_as_ushort(__float2half(l1)) << 16);
    int chunk = (c >> 6) * 16 + ((c >> 4) & 3) * 4 + (d2 >> 4);
    int oi = chunk * 256 + (((d2 >> 2) & 3) * 16 + (c & 15)) * 4 + (d2 & 3);
    epk_hi[oi] = hp;
    epk_lo[oi] = lp;
    int d0 = d2 * 2;
    eT[(size_t)d0 * C_ + c]       = v.x;
    eT[(size_t)(d0 + 1) * C_ + c] = v.y;

    // per-code work: used-flag zero + e2 numpy pairwise-8 replica
    if (gid < C_) {
        used[gid] = 0.0f;
        const float* row = embed + (size_t)gid * D_;
        {
#pragma clang fp contract(off)
            float r[8];
#pragma unroll
            for (int j = 0; j < 8; ++j) { float vv = row[j]; r[j] = vv * vv; }
            for (int i = 8; i < D_; i += 8) {
#pragma unroll
                for (int j = 0; j < 8; ++j) { float vv = row[i + j]; r[j] = r[j] + vv * vv; }
            }
            e2[gid] = ((r[0] + r[1]) + (r[2] + r[3])) + ((r[4] + r[5]) + (r[6] + r[7]));
        }
    }
    if (gid == 0) { accum[0] = 0.0f; nflag[0] = 0; }
}

// ---------------- MFMA prefilter argmin (fp16 2-term, x-frags pinned in VGPRs) ----------------
// 1024 blocks x 4 waves. Block = 64 points; wave w covers codes {rnd*64 + w*16 .. +15}, rnd=0..15.
__global__ __launch_bounds__(256) __attribute__((amdgpu_waves_per_eu(4, 4)))
void vq_mfma_kernel(
    const float* __restrict__ x, const u32* __restrict__ epk_hi, const u32* __restrict__ epk_lo,
    const float* __restrict__ e2, float* __restrict__ idx_f, int* __restrict__ idx_i,
    int* __restrict__ flagged, int* __restrict__ nflag)
{
    __shared__ float mv1[4][64];
    __shared__ int   mi1[4][64];
    __shared__ float mv2[4][64];

    const int g  = blockIdx.x;
    const int b  = g >> 6;
    const int t0 = (g & 63) << 6;
    const int tid = threadIdx.x;
    const int w  = tid >> 6;      // wave 0..3
    const int l  = tid & 63;
    const int r  = l & 15;        // point col / code row within 16x16 tile
    const int q  = l >> 4;        // k-group

    // ---- one-time: gather x fragments (fp16 RNE) into 64 VGPRs ----
    // strip s: point t0+16s+r ; kstep t: dims 32t + 8q + j
    i32x4 xf[4][4];
    {
        const float* xp = x + (size_t)b * ((size_t)D_ * T_) + t0 + r;
#pragma unroll
        for (int s = 0; s < 4; ++s) {
#pragma unroll
            for (int t = 0; t < 4; ++t) {
                float f[8];
#pragma unroll
                for (int j = 0; j < 8; ++j)
                    f[j] = xp[16 * s + (size_t)(32 * t + 8 * q + j) * T_];
                i32x4 pk;
                pk.x = (int)pack_h2(f[0], f[1]);
                pk.y = (int)pack_h2(f[2], f[3]);
                pk.z = (int)pack_h2(f[4], f[5]);
                pk.w = (int)pack_h2(f[6], f[7]);
                xf[s][t] = pk;
            }
        }
    }
    // remat blocker: fragments become asm-defined -> compiler must keep them resident
#pragma unroll
    for (int s = 0; s < 4; ++s)
#pragma unroll
        for (int t = 0; t < 4; ++t)
            asm volatile("" : "+v"(xf[s][t]));

    float rv1[4], rv2[4];
    int   ri1[4];
#pragma unroll
    for (int s = 0; s < 4; ++s) { rv1[s] = 3.4e38f; rv2[s] = 3.4e38f; ri1[s] = 0; }

    // per-lane e base (u32): wave w chunk base = w*4*256, + l*4 within chunk
    const u32* ephi = epk_hi + w * 1024 + l * 4;
    const u32* eplo = epk_lo + w * 1024 + l * 4;
    const int cbaseq = w * 16 + 4 * q;

    for (int rnd = 0; rnd < 16; ++rnd) {
        f32x4 eev = *reinterpret_cast<const f32x4*>(e2 + rnd * 64 + cbaseq);
        f32x4 acc[4];
#pragma unroll
        for (int s = 0; s < 4; ++s) acc[s] = f32x4{0.f, 0.f, 0.f, 0.f};

        __builtin_amdgcn_s_setprio(1);
#pragma unroll
        for (int t = 0; t < 4; ++t) {
            i32x4 eh = *reinterpret_cast<const i32x4*>(ephi + t * 256);
            i32x4 el = *reinterpret_cast<const i32x4*>(eplo + t * 256);
#pragma unroll
            for (int s = 0; s < 4; ++s) {
                acc[s] = __builtin_amdgcn_mfma_f32_16x16x32_f16(as_fp16x8(eh), as_fp16x8(xf[s][t]), acc[s], 0, 0, 0);
                acc[s] = __builtin_amdgcn_mfma_f32_16x16x32_f16(as_fp16x8(el), as_fp16x8(xf[s][t]), acc[s], 0, 0, 0);
            }
        }
        __builtin_amdgcn_s_setprio(0);
        ephi += 4096; eplo += 4096;

        // D: col = l&15 -> point 16s+r ; row = 4q+reg -> code rnd*64 + w*16 + 4q + reg
#pragma unroll
        for (int s = 0; s < 4; ++s) {
#pragma unroll
            for (int reg = 0; reg < 4; ++reg) {
                float sc = fmaf(-2.0f, acc[s][reg], eev[reg]);
                int c = rnd * 64 + cbaseq + reg;
                if (sc < rv1[s]) { rv2[s] = rv1[s]; rv1[s] = sc; ri1[s] = c; }
                else rv2[s] = fminf(rv2[s], sc);
            }
        }
    }

    // ---- merge across the 4 q-lane-groups per strip (within wave) ----
#pragma unroll
    for (int s = 0; s < 4; ++s) {
        float v1 = rv1[s], v2 = rv2[s];
        int   i1 = ri1[s];
#pragma unroll
        for (int mo = 0; mo < 2; ++mo) {
            int m = 16 << mo;
            float ov1 = __shfl_xor(v1, m, 64);
            int   oi1 = __shfl_xor(i1, m, 64);
            float ov2 = __shfl_xor(v2, m, 64);
            float nv2 = fminf(fmaxf(v1, ov1), fminf(v2, ov2));
            if (ov1 < v1 || (ov1 == v1 && oi1 < i1)) { v1 = ov1; i1 = oi1; }
            v2 = nv2;
        }
        if (q == 0) { mv1[w][16 * s + r] = v1; mi1[w][16 * s + r] = i1; mv2[w][16 * s + r] = v2; }
    }
    __syncthreads();

    // ---- merge across waves; write provisional idx; flag near-ties ----
    if (tid < 64) {
        float V1 = 3.4e38f, V2 = 3.4e38f;
        int   I1 = 0;
#pragma unroll
        for (int w2 = 0; w2 < 4; ++w2) {
            float a1 = mv1[w2][tid]; int ai = mi1[w2][tid]; float a2 = mv2[w2][tid];
            if (a1 < V1 || (a1 == V1 && ai < I1)) { V2 = fminf(V2, V1); V1 = a1; I1 = ai; }
            else V2 = fminf(V2, a1);
            V2 = fminf(V2, a2);
        }
        int n = g * 64 + tid;
        idx_i[n] = I1;
        idx_f[n] = (float)I1;
        if (V2 - V1 < MARGIN) { int pos = atomicAdd(nflag, 1); flagged[pos] = n; }
    }
}

// ---------------- exact numpy-replica rescore of flagged points (batched x8) ----------------
__global__ __launch_bounds__(256) void vq_refine_kernel(
    const float* __restrict__ x, const float* __restrict__ eT,
    const float* __restrict__ e2,
    const int* __restrict__ flagged, const int* __restrict__ nflag,
    float* __restrict__ idx_f, int* __restrict__ idx_i)
{
    __shared__ float xs[RB][D_];
    __shared__ float r8s[RB][8];
    __shared__ float xxs[RB];
    __shared__ float wvv[RB][4];
    __shared__ int   wvi[RB][4];

    const int tid = threadIdx.x;
    const int wv_ = tid >> 6;
    const int l   = tid & 63;
    const int total = *nflag;

    for (int base = blockIdx.x * RB; base < total; base += gridDim.x * RB) {
        __syncthreads();
#pragma unroll
        for (int e = 0; e < RB * D_ / 256; ++e) {
            int idx = tid + e * 256;
            int k = idx >> 7, d = idx & 127;
            float v = 0.f;
            int fi = base + k;
            if (fi < total) {
                int n = flagged[fi];
                int bb = n >> 12, t = n & (T_ - 1);
                v = x[(size_t)bb * ((size_t)D_ * T_) + (size_t)d * T_ + t];
            }
            xs[k][d] = v;
        }
        __syncthreads();

        if (tid < RB * 8) {
#pragma clang fp contract(off)
            int k = tid >> 3, j = tid & 7;
            float v0 = xs[k][j];
            float rj = v0 * v0;
            for (int i = 8; i < D_; i += 8) { float v = xs[k][i + j]; rj = rj + v * v; }
            r8s[k][j] = rj;
        }
        __syncthreads();
        if (tid < RB) {
#pragma clang fp contract(off)
            xxs[tid] = ((r8s[tid][0] + r8s[tid][1]) + (r8s[tid][2] + r8s[tid][3]))
                     + ((r8s[tid][4] + r8s[tid][5]) + (r8s[tid][6] + r8s[tid][7]));
        }
        __syncthreads();

        float acc[4][RB];
#pragma unroll
        for (int k2 = 0; k2 < 4; ++k2)
#pragma unroll
            for (int k = 0; k < RB; ++k) acc[k2][k] = 0.f;

        const float* ep = eT + wv_ * 256 + l;
        for (int d = 0; d < D_; ++d) {
            const float* rowp = ep + (size_t)d * C_;
            float ev0 = rowp[0], ev1 = rowp[64], ev2 = rowp[128], ev3 = rowp[192];
#pragma unroll
            for (int k = 0; k < RB; ++k) {
                float xv = xs[k][d];
                acc[0][k] = fmaf(xv, ev0, acc[0][k]);
                acc[1][k] = fmaf(xv, ev1, acc[1][k]);
                acc[2][k] = fmaf(xv, ev2, acc[2][k]);
                acc[3][k] = fmaf(xv, ev3, acc[3][k]);
            }
        }

        float e2v[4];
#pragma unroll
        for (int k2 = 0; k2 < 4; ++k2) e2v[k2] = e2[wv_ * 256 + 64 * k2 + l];

#pragma unroll
        for (int k = 0; k < RB; ++k) {
            float xx = xxs[k];
            float best = 3.4e38f;
            int   bi = 0;
#pragma unroll
            for (int k2 = 0; k2 < 4; ++k2) {
                int c = wv_ * 256 + 64 * k2 + l;
                float s;
                {
#pragma clang fp contract(off)
                    s = (xx - 2.0f * acc[k2][k]) + e2v[k2];
                }
                if (s < best) { best = s; bi = c; }
            }
#pragma unroll
            for (int m = 1; m <= 32; m <<= 1) {
                float ov = __shfl_xor(best, m, 64);
                int   oc = __shfl_xor(bi, m, 64);
                if (ov < best || (ov == best && oc < bi)) { best = ov; bi = oc; }
            }
            if (l == 0) { wvv[k][wv_] = best; wvi[k][wv_] = bi; }
        }
        __syncthreads();
        if (tid < RB) {
            int k = tid;
            if (base + k < total) {
                float V = wvv[k][0]; int I = wvi[k][0];
#pragma unroll
                for (int w2 = 1; w2 < 4; ++w2)
                    if (wvv[k][w2] < V || (wvv[k][w2] == V && wvi[k][w2] < I)) { V = wvv[k][w2]; I = wvi[k][w2]; }
                int n = flagged[base + k];
                idx_i[n] = I;
                idx_f[n] = (float)I;
            }
        }
    }
}

// ---------------- gather + loss partials + used-flags ----------------
__global__ __launch_bounds__(256) void vq_gather_kernel(
    const float* __restrict__ x, const float* __restrict__ embed,
    const int* __restrict__ idx_i, float* __restrict__ out_q,
    float* __restrict__ accum, float* __restrict__ used)
{
    __shared__ int sidx[64];
    __shared__ float red[256];

    const int g  = blockIdx.x;
    const int b  = g >> 6;
    const int t0 = (g & 63) << 6;
    const int tid = threadIdx.x;

    if (tid < 64) {
        int ci = idx_i[g * 64 + tid];
        sidx[tid] = ci;
        used[ci] = 1.0f;
    }
    __syncthreads();

    const float* xb = x     + (size_t)b * ((size_t)D_ * T_) + t0;
    float*       ob = out_q + (size_t)b * ((size_t)D_ * T_) + t0;

    float local = 0.f;
#pragma unroll
    for (int k = 0; k < 32; ++k) {
        int e = tid + 256 * k;
        int d = e >> 6, tt = e & 63;
        float qv = embed[(size_t)sidx[tt] * D_ + d];
        float xv = xb[(size_t)d * T_ + tt];
        ob[(size_t)d * T_ + tt] = qv;
        float df = xv - qv;
        local += df * df;
    }

    red[tid] = local;
    __syncthreads();
    for (int st = 128; st > 0; st >>= 1) {
        if (tid < st) red[tid] += red[tid + st];
        __syncthreads();
    }
    if (tid == 0) atomicAdd(accum, red[0]);
}

// ---------------- finalize ----------------
__global__ __launch_bounds__(256) void vq_final_kernel(
    const float* __restrict__ used, const float* __restrict__ accum,
    float* __restrict__ out_loss, float* __restrict__ out_util)
{
    __shared__ float red[256];
    int tid = threadIdx.x;
    float s = 0.f;
    for (int k = tid; k < C_; k += 256) s += used[k];
    red[tid] = s;
    __syncthreads();
    for (int st = 128; st > 0; st >>= 1) {
        if (tid < st) red[tid] += red[tid + st];
        __syncthreads();
    }
    if (tid == 0) {
        out_loss[0] = 2.0f * accum[0] / (float)((size_t)N_ * D_);
        out_util[0] = red[0] / (float)C_;
    }
}

extern "C" void kernel_launch(void* const* d_in, const int* in_sizes, int n_in,
                              void* d_out, int out_size, void* d_ws, size_t ws_size,
                              hipStream_t stream) {
    const float* x     = (const float*)d_in[0];
    const float* embed = (const float*)d_in[1];

    float* out      = (float*)d_out;
    float* out_q    = out;                              // 8388608
    float* idx_f    = out + (size_t)B_ * D_ * T_;       // 65536
    float* out_loss = idx_f + N_;                       // 1
    float* out_util = out_loss + 1;                     // 1

    float* ws      = (float*)d_ws;
    float* e2      = ws;                                 // [0 .. 1024)
    float* used    = ws + 1024;                          // [1024 .. 2048)
    int*   idx_i   = (int*)(ws + 2048);                  // [2048 .. 67584)
    float* accum   = ws + 67584;                         // [67584]
    int*   nflag   = (int*)(ws + 67585);                 // [67585]
    int*   flagged = (int*)(ws + 67588);                 // [67588 .. 133124)
    u32*   epk_hi  = (u32*)(ws + 133124);                // 65536 u32, 16B-aligned
    u32*   epk_lo  = (u32*)(ws + 198660);                // 65536 u32, 16B-aligned
    float* eT      = ws + 264196;                        // 131072 f32, 16B-aligned

    vq_prep_kernel  <<<256, 256, 0, stream>>>(embed, e2, epk_hi, epk_lo, eT, used, accum, nflag);
    vq_mfma_kernel  <<<N_ / 64, 256, 0, stream>>>(x, epk_hi, epk_lo, e2, idx_f, idx_i, flagged, nflag);
    vq_refine_kernel<<<256, 256, 0, stream>>>(x, eT, e2, flagged, nflag, idx_f, idx_i);
    vq_gather_kernel<<<N_ / 64, 256, 0, stream>>>(x, embed, idx_i, out_q, accum, used);
    vq_final_kernel <<<1, 256, 0, stream>>>(used, accum, out_loss, out_util);
}